// Round 5
// baseline (132.734 us; speedup 1.0000x reference)
//
#include <hip/hip_runtime.h>

#define NC 9
#define BLOCK 256

// ws layout: ws[0..8] = sum w*p_c ; ws[9..17] = sum onehot*w*p_c ; ws[18..26] = sum onehot*w

__global__ __launch_bounds__(BLOCK) void dice_partial(
    const float* __restrict__ logits,
    const int*   __restrict__ targets,
    float*       __restrict__ ws,
    int n)
{
    __shared__ float tile[BLOCK * NC];   // 9216 B

    float sWP[NC], sI[NC], sOH[NC];
    #pragma unroll
    for (int c = 0; c < NC; ++c) { sWP[c] = 0.f; sI[c] = 0.f; sOH[c] = 0.f; }

    const int tid = threadIdx.x;
    const int nChunks = (n + BLOCK - 1) / BLOCK;

    for (int chunk = blockIdx.x; chunk < nChunks; chunk += gridDim.x) {
        const int base  = chunk * BLOCK;
        const int elems = min(BLOCK * NC, (n - base) * NC);
        const float* g  = logits + (size_t)base * NC;

        // coalesced global -> LDS staging (9 contiguous loads per thread)
        #pragma unroll
        for (int k = 0; k < NC; ++k) {
            const int idx = tid + k * BLOCK;
            if (idx < elems) tile[idx] = g[idx];
        }
        __syncthreads();

        const int tok = base + tid;
        if (tok < n) {
            const int t    = targets[tok];
            const bool last = (tok == n - 1);
            const int tn   = last ? 0 : targets[tok + 1];

            // boundary weight, replicating reference overwrite order
            float w = 1.0f;
            if (t == 1) w = 3.0f;                    // B-PERSON
            const int nxt_dup = last ? t : tn;       // shifted padded with last elem
            if (t == 2 && nxt_dup != 2) w = 2.5f;    // I-PERSON end
            if (!last && tn == 1) w = 1.5f;          // token before a B (overwrites)

            // softmax over 9 classes (LDS read: bank = 9*l mod 32 -> conflict-free)
            float v[NC];
            #pragma unroll
            for (int c = 0; c < NC; ++c) v[c] = tile[tid * NC + c];
            float m = v[0];
            #pragma unroll
            for (int c = 1; c < NC; ++c) m = fmaxf(m, v[c]);
            float s = 0.f;
            #pragma unroll
            for (int c = 0; c < NC; ++c) { v[c] = __expf(v[c] - m); s += v[c]; }
            const float inv = __builtin_amdgcn_rcpf(s);

            #pragma unroll
            for (int c = 0; c < NC; ++c) {
                const float p = v[c] * inv;
                const bool hit = (t == c);
                sWP[c] += w * p;
                sI[c]  += hit ? w * p : 0.f;
                sOH[c] += hit ? w : 0.f;
            }
        }
        __syncthreads();
    }

    // wave-level shuffle reduction (64 lanes)
    #pragma unroll
    for (int off = 32; off; off >>= 1) {
        #pragma unroll
        for (int c = 0; c < NC; ++c) {
            sWP[c] += __shfl_down(sWP[c], off);
            sI[c]  += __shfl_down(sI[c], off);
            sOH[c] += __shfl_down(sOH[c], off);
        }
    }

    const int lane = tid & 63;
    const int wid  = tid >> 6;
    __syncthreads();               // tile reuse
    if (lane == 0) {
        #pragma unroll
        for (int c = 0; c < NC; ++c) {
            tile[wid * 32 + c]      = sWP[c];
            tile[wid * 32 + 9 + c]  = sI[c];
            tile[wid * 32 + 18 + c] = sOH[c];
        }
    }
    __syncthreads();
    if (tid < 27) {
        const float sum = tile[tid] + tile[32 + tid] + tile[64 + tid] + tile[96 + tid];
        atomicAdd(&ws[tid], sum);
    }
}

__global__ void dice_final(const float* __restrict__ ws, float* __restrict__ out)
{
    if (threadIdx.x == 0 && blockIdx.x == 0) {
        float acc = 0.f;
        #pragma unroll
        for (int c = 0; c < NC; ++c) {
            const float inter = ws[9 + c];
            const float den   = ws[c] + ws[18 + c];
            acc += (2.f * inter + 1e-5f) / (den + 1e-5f);
        }
        out[0] = 1.f - acc * (1.f / 9.f);
    }
}

extern "C" void kernel_launch(void* const* d_in, const int* in_sizes, int n_in,
                              void* d_out, int out_size, void* d_ws, size_t ws_size,
                              hipStream_t stream)
{
    const float* logits  = (const float*)d_in[0];
    const int*   targets = (const int*)d_in[1];
    float*       out     = (float*)d_out;
    float*       ws      = (float*)d_ws;
    const int n = in_sizes[1];           // token count (in_sizes[0] = n*9)

    hipMemsetAsync(ws, 0, 27 * sizeof(float), stream);

    const int nChunks = (n + BLOCK - 1) / BLOCK;
    const int grid = nChunks < 2048 ? nChunks : 2048;
    dice_partial<<<grid, BLOCK, 0, stream>>>(logits, targets, ws, n);
    dice_final<<<1, 64, 0, stream>>>(ws, out);
}

// Round 6
// 96.087 us; speedup vs baseline: 1.3814x; 1.3814x over previous
//
#include <hip/hip_runtime.h>

#define NC 9
#define BLOCK 256
#define TILE_F4 (BLOCK * NC / 4)   // 576 float4s = 2304 floats = 9216 B

// ws layout: ws[0..8] = sum w*p_c ; ws[9..17] = sum onehot*w*p_c ; ws[18..26] = sum onehot*w

__global__ __launch_bounds__(BLOCK) void dice_partial(
    const float* __restrict__ logits,
    const int*   __restrict__ targets,
    float*       __restrict__ ws,
    int n)
{
    __shared__ __align__(16) float tile[BLOCK * NC];   // 9216 B

    float sWP[NC], sI[NC], sOH[NC];
    #pragma unroll
    for (int c = 0; c < NC; ++c) { sWP[c] = 0.f; sI[c] = 0.f; sOH[c] = 0.f; }

    const int tid = threadIdx.x;
    const int nChunks = (n + BLOCK - 1) / BLOCK;

    for (int chunk = blockIdx.x; chunk < nChunks; chunk += gridDim.x) {
        const int base = chunk * BLOCK;
        const float* g = logits + (size_t)base * NC;

        if (base + BLOCK <= n) {
            // full chunk: vectorized coalesced staging, 16 B/lane
            const float4* g4 = reinterpret_cast<const float4*>(g);
            float4*       t4 = reinterpret_cast<float4*>(tile);
            t4[tid]          = g4[tid];
            t4[tid + BLOCK]  = g4[tid + BLOCK];
            if (tid < TILE_F4 - 2 * BLOCK)           // 576 - 512 = 64
                t4[tid + 2 * BLOCK] = g4[tid + 2 * BLOCK];
        } else {
            // tail chunk: scalar guarded staging
            const int elems = (n - base) * NC;
            #pragma unroll
            for (int k = 0; k < NC; ++k) {
                const int idx = tid + k * BLOCK;
                if (idx < elems) tile[idx] = g[idx];
            }
        }
        __syncthreads();

        const int tok = base + tid;
        if (tok < n) {
            const int t    = targets[tok];
            const bool last = (tok == n - 1);
            const int tn   = last ? 0 : targets[tok + 1];

            // boundary weight, replicating reference overwrite order
            float w = 1.0f;
            if (t == 1) w = 3.0f;                    // B-PERSON
            const int nxt_dup = last ? t : tn;       // shifted padded with last elem
            if (t == 2 && nxt_dup != 2) w = 2.5f;    // I-PERSON end
            if (!last && tn == 1) w = 1.5f;          // token before a B (overwrites)

            // softmax over 9 classes (LDS read: bank = 9*l mod 32 -> conflict-free)
            float v[NC];
            #pragma unroll
            for (int c = 0; c < NC; ++c) v[c] = tile[tid * NC + c];
            float m = v[0];
            #pragma unroll
            for (int c = 1; c < NC; ++c) m = fmaxf(m, v[c]);
            float s = 0.f;
            #pragma unroll
            for (int c = 0; c < NC; ++c) { v[c] = __expf(v[c] - m); s += v[c]; }
            const float inv = __builtin_amdgcn_rcpf(s);

            #pragma unroll
            for (int c = 0; c < NC; ++c) {
                const float p = v[c] * inv;
                const bool hit = (t == c);
                sWP[c] += w * p;
                sI[c]  += hit ? w * p : 0.f;
                sOH[c] += hit ? w : 0.f;
            }
        }
        __syncthreads();
    }

    // wave-level shuffle reduction (64 lanes)
    #pragma unroll
    for (int off = 32; off; off >>= 1) {
        #pragma unroll
        for (int c = 0; c < NC; ++c) {
            sWP[c] += __shfl_down(sWP[c], off);
            sI[c]  += __shfl_down(sI[c], off);
            sOH[c] += __shfl_down(sOH[c], off);
        }
    }

    const int lane = tid & 63;
    const int wid  = tid >> 6;
    __syncthreads();               // tile reuse
    if (lane == 0) {
        #pragma unroll
        for (int c = 0; c < NC; ++c) {
            tile[wid * 32 + c]      = sWP[c];
            tile[wid * 32 + 9 + c]  = sI[c];
            tile[wid * 32 + 18 + c] = sOH[c];
        }
    }
    __syncthreads();
    if (tid < 27) {
        const float sum = tile[tid] + tile[32 + tid] + tile[64 + tid] + tile[96 + tid];
        atomicAdd(&ws[tid], sum);
    }
}

__global__ void dice_final(const float* __restrict__ ws, float* __restrict__ out)
{
    if (threadIdx.x == 0 && blockIdx.x == 0) {
        float acc = 0.f;
        #pragma unroll
        for (int c = 0; c < NC; ++c) {
            const float inter = ws[9 + c];
            const float den   = ws[c] + ws[18 + c];
            acc += (2.f * inter + 1e-5f) / (den + 1e-5f);
        }
        out[0] = 1.f - acc * (1.f / 9.f);
    }
}

extern "C" void kernel_launch(void* const* d_in, const int* in_sizes, int n_in,
                              void* d_out, int out_size, void* d_ws, size_t ws_size,
                              hipStream_t stream)
{
    const float* logits  = (const float*)d_in[0];
    const int*   targets = (const int*)d_in[1];
    float*       out     = (float*)d_out;
    float*       ws      = (float*)d_ws;
    const int n = in_sizes[1];           // token count (in_sizes[0] = n*9)

    hipMemsetAsync(ws, 0, 27 * sizeof(float), stream);

    const int nChunks = (n + BLOCK - 1) / BLOCK;
    const int grid = nChunks < 2048 ? nChunks : 2048;
    dice_partial<<<grid, BLOCK, 0, stream>>>(logits, targets, ws, n);
    dice_final<<<1, 64, 0, stream>>>(ws, out);
}

// Round 9
// 82.767 us; speedup vs baseline: 1.6037x; 1.1609x over previous
//
#include <hip/hip_runtime.h>

#define NC 9
#define BLOCK 256
#define TPT 4                       // tokens per thread
#define CHUNK (BLOCK * TPT)         // 1024 tokens per block-iteration
#define GRID 2048

// partials layout: partials[block*32 + idx], idx 0..8 = sum w*p_c,
// 9..17 = sum onehot*w*p_c, 18..26 = sum onehot*w

__global__ __launch_bounds__(BLOCK) void dice_partial(
    const float* __restrict__ logits,
    const int*   __restrict__ targets,
    float*       __restrict__ partials,
    int n)
{
    float sWP[NC], sI[NC], sOH[NC];
    #pragma unroll
    for (int c = 0; c < NC; ++c) { sWP[c] = 0.f; sI[c] = 0.f; sOH[c] = 0.f; }

    const int tid = threadIdx.x;
    const int nChunks = (n + CHUNK - 1) / CHUNK;

    for (int chunk = blockIdx.x; chunk < nChunks; chunk += gridDim.x) {
        const int base = chunk * CHUNK + tid * TPT;   // first token of this thread

        if (base + TPT <= n) {
            // ---- fast path: 4 tokens, 9 x float4 contiguous 144 B ----
            const float4* g4 = reinterpret_cast<const float4*>(logits + (size_t)base * NC);
            float f[TPT * NC];
            #pragma unroll
            for (int k = 0; k < 9; ++k) {
                const float4 q = g4[k];
                f[4 * k]     = q.x;
                f[4 * k + 1] = q.y;
                f[4 * k + 2] = q.z;
                f[4 * k + 3] = q.w;
            }
            const int4 t4 = *reinterpret_cast<const int4*>(targets + base);
            int tg[TPT];
            tg[0] = t4.x; tg[1] = t4.y; tg[2] = t4.z; tg[3] = t4.w;
            const int tExtra = (base + TPT < n) ? targets[base + TPT] : 0;
            const bool lastIsGlobalEnd = (base + TPT == n);

            #pragma unroll
            for (int j = 0; j < TPT; ++j) {
                const int  t    = tg[j];
                const bool last = (j == TPT - 1) && lastIsGlobalEnd;
                const int  tn   = (j < TPT - 1) ? tg[j + 1] : tExtra;

                float w = 1.0f;
                if (t == 1) w = 3.0f;                    // B-PERSON
                const int nxt_dup = last ? t : tn;       // shift padded with last elem
                if (t == 2 && nxt_dup != 2) w = 2.5f;    // I-PERSON end
                if (!last && tn == 1) w = 1.5f;          // token before a B (overwrites)

                float v[NC];
                #pragma unroll
                for (int c = 0; c < NC; ++c) v[c] = f[j * NC + c];
                float m = v[0];
                #pragma unroll
                for (int c = 1; c < NC; ++c) m = fmaxf(m, v[c]);
                float s = 0.f;
                #pragma unroll
                for (int c = 0; c < NC; ++c) { v[c] = __expf(v[c] - m); s += v[c]; }
                const float inv = __builtin_amdgcn_rcpf(s);

                #pragma unroll
                for (int c = 0; c < NC; ++c) {
                    const float p   = v[c] * inv;
                    const bool  hit = (t == c);
                    sWP[c] += w * p;
                    sI[c]  += hit ? w * p : 0.f;
                    sOH[c] += hit ? w : 0.f;
                }
            }
        } else {
            // ---- tail path: per-token guarded scalar ----
            for (int j = 0; j < TPT; ++j) {
                const int a = base + j;
                if (a >= n) break;
                const int  t    = targets[a];
                const bool last = (a == n - 1);
                const int  tn   = last ? 0 : targets[a + 1];

                float w = 1.0f;
                if (t == 1) w = 3.0f;
                const int nxt_dup = last ? t : tn;
                if (t == 2 && nxt_dup != 2) w = 2.5f;
                if (!last && tn == 1) w = 1.5f;

                float v[NC];
                #pragma unroll
                for (int c = 0; c < NC; ++c) v[c] = logits[(size_t)a * NC + c];
                float m = v[0];
                #pragma unroll
                for (int c = 1; c < NC; ++c) m = fmaxf(m, v[c]);
                float s = 0.f;
                #pragma unroll
                for (int c = 0; c < NC; ++c) { v[c] = __expf(v[c] - m); s += v[c]; }
                const float inv = __builtin_amdgcn_rcpf(s);

                #pragma unroll
                for (int c = 0; c < NC; ++c) {
                    const float p   = v[c] * inv;
                    const bool  hit = (t == c);
                    sWP[c] += w * p;
                    sI[c]  += hit ? w * p : 0.f;
                    sOH[c] += hit ? w : 0.f;
                }
            }
        }
    }

    // ---- wave shuffle reduction (64 lanes) ----
    #pragma unroll
    for (int off = 32; off; off >>= 1) {
        #pragma unroll
        for (int c = 0; c < NC; ++c) {
            sWP[c] += __shfl_down(sWP[c], off);
            sI[c]  += __shfl_down(sI[c], off);
            sOH[c] += __shfl_down(sOH[c], off);
        }
    }

    // ---- cross-wave LDS reduction, then per-block partial store ----
    __shared__ float red[4][32];
    const int lane = tid & 63;
    const int wid  = tid >> 6;
    if (lane == 0) {
        #pragma unroll
        for (int c = 0; c < NC; ++c) {
            red[wid][c]      = sWP[c];
            red[wid][9 + c]  = sI[c];
            red[wid][18 + c] = sOH[c];
        }
    }
    __syncthreads();
    if (tid < 27) {
        partials[blockIdx.x * 32 + tid] =
            red[0][tid] + red[1][tid] + red[2][tid] + red[3][tid];
    }
}

__global__ __launch_bounds__(1024) void dice_reduce(
    const float* __restrict__ partials,
    float*       __restrict__ out,
    int nblocks)
{
    const int c = threadIdx.x & 31;   // class-slot 0..31 (27 used)
    const int r = threadIdx.x >> 5;   // 0..31
    float s = 0.f;
    if (c < 27) {
        for (int b = r; b < nblocks; b += 32)
            s += partials[b * 32 + c];
    }
    __shared__ float acc[32][33];
    acc[r][c] = s;
    __syncthreads();
    if (threadIdx.x == 0) {
        float A[27];
        #pragma unroll
        for (int i = 0; i < 27; ++i) {
            float tot = 0.f;
            for (int k = 0; k < 32; ++k) tot += acc[k][i];
            A[i] = tot;
        }
        float dsum = 0.f;
        #pragma unroll
        for (int cc = 0; cc < NC; ++cc) {
            const float inter = A[9 + cc];
            const float den   = A[cc] + A[18 + cc];
            dsum += (2.f * inter + 1e-5f) / (den + 1e-5f);
        }
        out[0] = 1.f - dsum * (1.f / 9.f);
    }
}

extern "C" void kernel_launch(void* const* d_in, const int* in_sizes, int n_in,
                              void* d_out, int out_size, void* d_ws, size_t ws_size,
                              hipStream_t stream)
{
    const float* logits   = (const float*)d_in[0];
    const int*   targets  = (const int*)d_in[1];
    float*       out      = (float*)d_out;
    float*       partials = (float*)d_ws;
    const int n = in_sizes[1];           // token count (in_sizes[0] = n*9)

    const int nChunks = (n + CHUNK - 1) / CHUNK;
    const int grid = nChunks < GRID ? nChunks : GRID;
    dice_partial<<<grid, BLOCK, 0, stream>>>(logits, targets, partials, n);
    dice_reduce<<<1, 1024, 0, stream>>>(partials, out, grid);
}